// Round 9
// baseline (436.060 us; speedup 1.0000x reference)
//
#include <hip/hip_runtime.h>
#include <stdint.h>

// Problem dims (fixed by the reference)
#define TT 256
#define SS 256
#define FF 1024
#define AA 256

typedef __attribute__((ext_vector_type(8))) short short8;
typedef __attribute__((ext_vector_type(4))) float floatx4;

// fp32 -> bf16 round-to-nearest-even
__device__ __forceinline__ unsigned short f2bf(float f) {
  unsigned int u = __float_as_uint(f);
  u += 0x7FFFu + ((u >> 16) & 1u);
  return (unsigned short)(u >> 16);
}

// async global->LDS, 16 B per lane; LDS dest = wave-uniform base + lane*16
__device__ __forceinline__ void gl_lds16(const unsigned short* g, unsigned short* l) {
  __builtin_amdgcn_global_load_lds(
      (__attribute__((address_space(1))) void*)(g),
      (__attribute__((address_space(3))) void*)(l), 16, 0, 0);
}

// ---------------------------------------------------------------------------
// Weight transpose + fp32->bf16:  WT[n][k] = bf16(W[k][n]).  W: K x N fp32.
// (fallback path)
// ---------------------------------------------------------------------------
__global__ void k_transpose_cvt(const float* __restrict__ W,
                                unsigned short* __restrict__ WT,
                                int K, int N) {
  __shared__ float tile[32][33];
  const int bk = blockIdx.x * 32, bn = blockIdx.y * 32;
  const int tx = threadIdx.x, ty = threadIdx.y;
  for (int i = ty; i < 32; i += 8)
    tile[i][tx] = W[(size_t)(bk + i) * N + bn + tx];
  __syncthreads();
  for (int i = ty; i < 32; i += 8)
    WT[(size_t)(bn + i) * K + bk + tx] = f2bf(tile[tx][i]);
}

// ---------------------------------------------------------------------------
// Bulk fp32 -> bf16 convert (fallback path).
// ---------------------------------------------------------------------------
__global__ __launch_bounds__(256) void k_cvt(const float* __restrict__ in,
                                             unsigned short* __restrict__ out,
                                             unsigned int n8) {
  unsigned int i = blockIdx.x * 256u + threadIdx.x;
  const unsigned int stride = gridDim.x * 256u;
  for (; i < n8; i += stride) {
    const size_t base = (size_t)i * 8;
    const floatx4 v0 = *(const floatx4*)(in + base);
    const floatx4 v1 = *(const floatx4*)(in + base + 4);
    ushort4 h0, h1;
    h0.x = f2bf(v0.x); h0.y = f2bf(v0.y); h0.z = f2bf(v0.z); h0.w = f2bf(v0.w);
    h1.x = f2bf(v1.x); h1.y = f2bf(v1.y); h1.z = f2bf(v1.z); h1.w = f2bf(v1.w);
    *(ushort4*)(out + base) = h0;
    *(ushort4*)(out + base + 4) = h1;
  }
}

// ---------------------------------------------------------------------------
// Fused prep: one dispatch does the full-batch fp32->bf16 convert AND the
// three weight transposes.
//   blocks [0, 2048):     grid-stride cvt of batch (65536x1024)
//   blocks [2048, 2304):  aT transpose   blocks [2304, 2560): bT transpose
//   blocks [2560, 3584):  gT transpose
// ---------------------------------------------------------------------------
__global__ __launch_bounds__(256) void k_prep(
    const float* __restrict__ batch, unsigned short* __restrict__ batchH,
    const float* __restrict__ a_w, unsigned short* __restrict__ aT,
    const float* __restrict__ b_w, unsigned short* __restrict__ bT,
    const float* __restrict__ g_w, unsigned short* __restrict__ gT) {
  const int bid = blockIdx.x;
  if (bid < 2048) {
    const unsigned int n8 = (unsigned int)((size_t)TT * SS * FF / 8);
    unsigned int i = bid * 256u + threadIdx.x;
    for (; i < n8; i += 2048u * 256u) {
      const size_t base = (size_t)i * 8;
      const floatx4 v0 = *(const floatx4*)(batch + base);
      const floatx4 v1 = *(const floatx4*)(batch + base + 4);
      ushort4 h0, h1;
      h0.x = f2bf(v0.x); h0.y = f2bf(v0.y); h0.z = f2bf(v0.z); h0.w = f2bf(v0.w);
      h1.x = f2bf(v1.x); h1.y = f2bf(v1.y); h1.z = f2bf(v1.z); h1.w = f2bf(v1.w);
      *(ushort4*)(batchH + base) = h0;
      *(ushort4*)(batchH + base + 4) = h1;
    }
  } else {
    const int t = bid - 2048;
    const float* W; unsigned short* WT; int N, bx, by;
    if (t < 256)      { W = a_w; WT = aT; N = AA; bx = t % 32;        by = t / 32; }
    else if (t < 512) { W = b_w; WT = bT; N = AA; bx = (t - 256) % 32; by = (t - 256) / 32; }
    else              { W = g_w; WT = gT; N = FF; bx = (t - 512) % 32; by = (t - 512) / 32; }
    const int K = FF;
    __shared__ float tile[32][33];
    const int bk = bx * 32, bn = by * 32;
    const int tx = threadIdx.x & 31, ty = threadIdx.x >> 5;
    for (int i = ty; i < 32; i += 8)
      tile[i][tx] = W[(size_t)(bk + i) * N + bn + tx];
    __syncthreads();
    for (int i = ty; i < 32; i += 8)
      WT[(size_t)(bn + i) * K + bk + tx] = f2bf(tile[tx][i]);
  }
}

// ---------------------------------------------------------------------------
// Shared pieces for the 256x256 / BK=64 / 8-wave 8-phase GEMM structure.
// LDS 128 KiB: A[2buf][2half][128][64] | B[...]; half-tiles staged via
// global_load_lds with counted vmcnt (never 0 mid-loop).
// T2 swizzle: LDS granule gl of row r holds global granule gl ^ (r&7)
// (pre-swizzled source, rule #21); reads use col ^ ((row&7)<<3)
// -> conflict-free (measured 0).
// ---------------------------------------------------------------------------
__device__ __forceinline__ void stage_half(const unsigned short* G, int ld,
                                           unsigned short* L, int tid) {
  // G points at (row0, k0) of a 128x64 half-tile, leading dim = ld elems.
  const int wave = tid >> 6, lane = tid & 63;
#pragma unroll
  for (int c = 0; c < 2; ++c) {
    const int chunk = c * 8 + wave;            // 16 chunks of 8 rows
    const int r = chunk * 8 + (lane >> 3);     // local row 0..127
    const int k8 = (lane & 7) ^ (lane >> 3);   // swizzled source 16B-granule
    gl_lds16(G + (size_t)r * ld + k8 * 8, L + chunk * 512);
  }
}

__device__ __forceinline__ short8 ldsfrag(const unsigned short* h, int row,
                                          int col) {
  return *(const short8*)&h[row * 64 + (col ^ ((row & 7) << 3))];
}

// The R3-verified K-loop (kept for k_bt256):
//   ph0: stage A0(kt+1); vmcnt(6)|0; barrier; read af0+bf; q00; barrier
//   ph1: stage A1(kt+1); read af1; q01; barrier
//   ph2: stage B0(kt+2); q10; barrier
//   ph3: stage B1(kt+2); q11; barrier
#define KLOOP_256(Ap, ldA, Bp, ldB, NKT)                                       \
  for (int kt = 0; kt < (NKT); ++kt) {                                         \
    const unsigned short* Ah = As + ((kt & 1) * 2 + wm) * 8192;                \
    const unsigned short* Bh = Bs + ((kt & 1) * 2 + (wn >> 1)) * 8192;         \
    const int nbuf = 1 - (kt & 1);                                             \
    if (kt + 1 < (NKT)) {                                                      \
      stage_half((Ap) + (size_t)(kt + 1) * 64, (ldA),                          \
                 As + (nbuf * 2 + 0) * 8192, tid);                             \
      asm volatile("s_waitcnt vmcnt(6)" ::: "memory");                         \
    } else {                                                                   \
      asm volatile("s_waitcnt vmcnt(0)" ::: "memory");                         \
    }                                                                          \
    asm volatile("s_barrier" ::: "memory");                                    \
    _Pragma("unroll") for (int i = 0; i < 4; ++i)                              \
        _Pragma("unroll") for (int ks = 0; ks < 2; ++ks)                       \
            af[i][ks] = ldsfrag(Ah, i * 16 + lr, ks * 32 + lq * 8);            \
    _Pragma("unroll") for (int j = 0; j < 4; ++j)                              \
        _Pragma("unroll") for (int ks = 0; ks < 2; ++ks)                       \
            bf[j][ks] = ldsfrag(Bh, brow + j * 16 + lr, ks * 32 + lq * 8);     \
    __builtin_amdgcn_s_setprio(1);                                             \
    _Pragma("unroll") for (int i = 0; i < 4; ++i)                              \
        _Pragma("unroll") for (int j = 0; j < 2; ++j)                          \
            _Pragma("unroll") for (int ks = 0; ks < 2; ++ks)                   \
                acc[i][j] = __builtin_amdgcn_mfma_f32_16x16x32_bf16(           \
                    af[i][ks], bf[j][ks], acc[i][j], 0, 0, 0);                 \
    __builtin_amdgcn_s_setprio(0);                                             \
    asm volatile("s_barrier" ::: "memory");                                    \
    if (kt + 1 < (NKT))                                                        \
      stage_half((Ap) + 128 * (ldA) + (size_t)(kt + 1) * 64, (ldA),            \
                 As + (nbuf * 2 + 1) * 8192, tid);                             \
    _Pragma("unroll") for (int i = 0; i < 4; ++i)                              \
        _Pragma("unroll") for (int ks = 0; ks < 2; ++ks)                       \
            af1[i][ks] = ldsfrag(Ah, 64 + i * 16 + lr, ks * 32 + lq * 8);      \
    __builtin_amdgcn_s_setprio(1);                                             \
    _Pragma("unroll") for (int i = 0; i < 4; ++i)                              \
        _Pragma("unroll") for (int j = 0; j < 2; ++j)                          \
            _Pragma("unroll") for (int ks = 0; ks < 2; ++ks)                   \
                acc[i][2 + j] = __builtin_amdgcn_mfma_f32_16x16x32_bf16(       \
                    af[i][ks], bf[2 + j][ks], acc[i][2 + j], 0, 0, 0);         \
    __builtin_amdgcn_s_setprio(0);                                             \
    asm volatile("s_barrier" ::: "memory");                                    \
    if (kt + 2 < (NKT))                                                        \
      stage_half((Bp) + (size_t)(kt + 2) * 64, (ldB),                          \
                 Bs + ((kt & 1) * 2 + 0) * 8192, tid);                         \
    __builtin_amdgcn_s_setprio(1);                                             \
    _Pragma("unroll") for (int i = 0; i < 4; ++i)                              \
        _Pragma("unroll") for (int j = 0; j < 2; ++j)                          \
            _Pragma("unroll") for (int ks = 0; ks < 2; ++ks)                   \
                acc[4 + i][j] = __builtin_amdgcn_mfma_f32_16x16x32_bf16(       \
                    af1[i][ks], bf[j][ks], acc[4 + i][j], 0, 0, 0);            \
    __builtin_amdgcn_s_setprio(0);                                             \
    asm volatile("s_barrier" ::: "memory");                                    \
    if (kt + 2 < (NKT))                                                        \
      stage_half((Bp) + 128 * (ldB) + (size_t)(kt + 2) * 64, (ldB),            \
                 Bs + ((kt & 1) * 2 + 1) * 8192, tid);                         \
    __builtin_amdgcn_s_setprio(1);                                             \
    _Pragma("unroll") for (int i = 0; i < 4; ++i)                              \
        _Pragma("unroll") for (int j = 0; j < 2; ++j)                          \
            _Pragma("unroll") for (int ks = 0; ks < 2; ++ks)                   \
                acc[4 + i][2 + j] = __builtin_amdgcn_mfma_f32_16x16x32_bf16(   \
                    af1[i][ks], bf[2 + j][ks], acc[4 + i][2 + j], 0, 0, 0);    \
    __builtin_amdgcn_s_setprio(0);                                             \
    asm volatile("s_barrier" ::: "memory");                                    \
  }

#define PROLOGUE_256(Ap, ldA, Bp, ldB)                                         \
  stage_half((Bp), (ldB), Bs + 0 * 8192, tid);                                 \
  stage_half((Bp) + 128 * (ldB), (ldB), Bs + 1 * 8192, tid);                   \
  stage_half((Ap), (ldA), As + 0 * 8192, tid);                                 \
  stage_half((Ap) + 128 * (ldA), (ldA), As + 1 * 8192, tid);                   \
  stage_half((Bp) + 64, (ldB), Bs + 2 * 8192, tid);                            \
  stage_half((Bp) + 128 * (ldB) + 64, (ldB), Bs + 3 * 8192, tid);

// ---------------------------------------------------------------------------
// Projection GEMM, m201-EXACT phase order: each phase = {reads -> stage ->
// barrier -> lgkmcnt(0) -> MFMA -> barrier}; the vmcnt gate lives at the END
// of the previous K-tile (ph3), NEVER between a phase's reads and its MFMA.
// Reads get the barrier-wait to complete -> lgkmcnt(0) is nearly free.
//   ph0(kt): read af0(8)+bf01(4);  stage A0(kt+1); bar; lgkm0; q00; bar
//   ph1(kt): read bf23(4);         stage A1(kt+1); bar; lgkm0; q01; bar
//   ph2(kt): read af1(8);          stage B0(kt+2); bar; lgkm0; q10; bar
//   ph3(kt): (no reads);           stage B1(kt+2); GATE; bar; q11; bar
// Gate ledger (issue order per thread, 2 loads per stage_half):
//   at ph3(kt) after issuing B1(kt+2): outstanding =
//     [A0(kt+1)2, A1(kt+1)2, B0(kt+2)2, B1(kt+2)2] = 8
//   -> vmcnt(4) completes A(kt+1)+B(kt+1)(older) = ALL of tile kt+1 (the gate
//      guards all four slots uniformly - no per-wave asymmetry).
//   kt = NKT-2: no B(kt+2) staged -> outstanding = A(NKT-1) 4 -> vmcnt(0).
//   kt = NKT-1: no gate (nothing read after).
//   Prologue: 12 loads; vmcnt(4) (leave B(1)); barrier.
// WAR: each slot's re-stage is issued >= 2 barriers after all reads of that
// slot drained (reads drain at their phase's pre-MFMA lgkmcnt(0)).
// ---------------------------------------------------------------------------
__global__ __launch_bounds__(512, 2) void k_proj5(
    const unsigned short* __restrict__ batchH,   // chunk base [mtiles*256][FF]
    const unsigned short* __restrict__ aT,
    const unsigned short* __restrict__ bT,
    const unsigned short* __restrict__ gT,
    const float* __restrict__ a_b, const float* __restrict__ b_b,
    const float* __restrict__ g_b,
    unsigned short* __restrict__ theta,
    unsigned short* __restrict__ phi,
    unsigned short* __restrict__ featsT,
    int mbase) {
  __shared__ unsigned short lds[65536];  // 128 KiB
  unsigned short* As = lds;              // [(buf*2+half)*8192]
  unsigned short* Bs = lds + 32768;

  // T1: bijective XCD-chunked swizzle (gridDim.x % 8 == 0)
  const int nwg = gridDim.x;
  const int hb = blockIdx.x;
  const int logical = (hb & 7) * (nwg >> 3) + (hb >> 3);
  const int nt = logical % 6;
  const int mtile = logical / 6;
  const int m0l = mtile * 256;   // chunk-local
  const int m0 = mbase + m0l;    // global (multiple of 256)

  const unsigned short* Wt; const float* bias; int nb0, mode;
  if (nt == 0)      { Wt = aT; bias = a_b; nb0 = 0;              mode = 0; }
  else if (nt == 1) { Wt = bT; bias = b_b; nb0 = 0;              mode = 1; }
  else              { Wt = gT; bias = g_b; nb0 = (nt - 2) * 256; mode = 2; }

  const int tid = threadIdx.x;
  const int wave = tid >> 6, lane = tid & 63;
  const int wm = wave >> 2, wn = wave & 3;
  const int lr = lane & 15, lq = lane >> 4;
  const int brow = (wn & 1) * 64;  // wave's local row base within its B half

  const unsigned short* Ap = batchH + (size_t)m0l * FF;  // [256][1024]
  const unsigned short* Bp = Wt + (size_t)nb0 * FF;      // [256][1024]

  floatx4 acc[8][4];
#pragma unroll
  for (int i = 0; i < 8; i++)
#pragma unroll
    for (int j = 0; j < 4; j++) acc[i][j] = (floatx4)0.0f;

  short8 af[4][2], af1[4][2], bf[4][2];
  const int NKT = FF / 64;  // 16

  // Prologue: stage tile0 + B(1); gate tile0 (vmcnt(4): B(1) in flight).
  PROLOGUE_256(Ap, FF, Bp, FF)
  asm volatile("s_waitcnt vmcnt(4)" ::: "memory");
  asm volatile("s_barrier" ::: "memory");

#pragma unroll 1
  for (int kt = 0; kt < NKT; ++kt) {
    const unsigned short* Ah = As + ((kt & 1) * 2 + wm) * 8192;
    const unsigned short* Bh = Bs + ((kt & 1) * 2 + (wn >> 1)) * 8192;
    const int nbuf = 1 - (kt & 1);

    // ---- ph0: read af0+bf01; stage A0(kt+1); bar; lgkm0; q00; bar ----
#pragma unroll
    for (int i = 0; i < 4; ++i)
#pragma unroll
      for (int ks = 0; ks < 2; ++ks)
        af[i][ks] = ldsfrag(Ah, i * 16 + lr, ks * 32 + lq * 8);
#pragma unroll
    for (int j = 0; j < 2; ++j)
#pragma unroll
      for (int ks = 0; ks < 2; ++ks)
        bf[j][ks] = ldsfrag(Bh, brow + j * 16 + lr, ks * 32 + lq * 8);
    if (kt + 1 < NKT)
      stage_half(Ap + (size_t)(kt + 1) * 64, FF, As + (nbuf * 2 + 0) * 8192,
                 tid);
    asm volatile("s_barrier" ::: "memory");
    asm volatile("s_waitcnt lgkmcnt(0)" ::: "memory");
    __builtin_amdgcn_s_setprio(1);
#pragma unroll
    for (int i = 0; i < 4; ++i)
#pragma unroll
      for (int j = 0; j < 2; ++j)
#pragma unroll
        for (int ks = 0; ks < 2; ++ks)
          acc[i][j] = __builtin_amdgcn_mfma_f32_16x16x32_bf16(
              af[i][ks], bf[j][ks], acc[i][j], 0, 0, 0);
    __builtin_amdgcn_s_setprio(0);
    asm volatile("s_barrier" ::: "memory");

    // ---- ph1: read bf23; stage A1(kt+1); bar; lgkm0; q01; bar ----
#pragma unroll
    for (int j = 2; j < 4; ++j)
#pragma unroll
      for (int ks = 0; ks < 2; ++ks)
        bf[j][ks] = ldsfrag(Bh, brow + j * 16 + lr, ks * 32 + lq * 8);
    if (kt + 1 < NKT)
      stage_half(Ap + 128 * FF + (size_t)(kt + 1) * 64, FF,
                 As + (nbuf * 2 + 1) * 8192, tid);
    asm volatile("s_barrier" ::: "memory");
    asm volatile("s_waitcnt lgkmcnt(0)" ::: "memory");
    __builtin_amdgcn_s_setprio(1);
#pragma unroll
    for (int i = 0; i < 4; ++i)
#pragma unroll
      for (int j = 0; j < 2; ++j)
#pragma unroll
        for (int ks = 0; ks < 2; ++ks)
          acc[i][2 + j] = __builtin_amdgcn_mfma_f32_16x16x32_bf16(
              af[i][ks], bf[2 + j][ks], acc[i][2 + j], 0, 0, 0);
    __builtin_amdgcn_s_setprio(0);
    asm volatile("s_barrier" ::: "memory");

    // ---- ph2: read af1; stage B0(kt+2); bar; lgkm0; q10; bar ----
#pragma unroll
    for (int i = 0; i < 4; ++i)
#pragma unroll
      for (int ks = 0; ks < 2; ++ks)
        af1[i][ks] = ldsfrag(Ah, 64 + i * 16 + lr, ks * 32 + lq * 8);
    if (kt + 2 < NKT)
      stage_half(Bp + (size_t)(kt + 2) * 64, FF,
                 Bs + ((kt & 1) * 2 + 0) * 8192, tid);
    asm volatile("s_barrier" ::: "memory");
    asm volatile("s_waitcnt lgkmcnt(0)" ::: "memory");
    __builtin_amdgcn_s_setprio(1);
#pragma unroll
    for (int i = 0; i < 4; ++i)
#pragma unroll
      for (int j = 0; j < 2; ++j)
#pragma unroll
        for (int ks = 0; ks < 2; ++ks)
          acc[4 + i][j] = __builtin_amdgcn_mfma_f32_16x16x32_bf16(
              af1[i][ks], bf[j][ks], acc[4 + i][j], 0, 0, 0);
    __builtin_amdgcn_s_setprio(0);
    asm volatile("s_barrier" ::: "memory");

    // ---- ph3: stage B1(kt+2); GATE(tile kt+1); bar; q11; bar ----
    if (kt + 2 < NKT)
      stage_half(Bp + 128 * FF + (size_t)(kt + 2) * 64, FF,
                 Bs + ((kt & 1) * 2 + 1) * 8192, tid);
    if (kt + 1 < NKT) {
      if (kt + 2 < NKT) asm volatile("s_waitcnt vmcnt(4)" ::: "memory");
      else              asm volatile("s_waitcnt vmcnt(0)" ::: "memory");
    }
    asm volatile("s_barrier" ::: "memory");
    __builtin_amdgcn_s_setprio(1);
#pragma unroll
    for (int i = 0; i < 4; ++i)
#pragma unroll
      for (int j = 0; j < 2; ++j)
#pragma unroll
        for (int ks = 0; ks < 2; ++ks)
          acc[4 + i][2 + j] = __builtin_amdgcn_mfma_f32_16x16x32_bf16(
              af1[i][ks], bf[2 + j][ks], acc[4 + i][2 + j], 0, 0, 0);
    __builtin_amdgcn_s_setprio(0);
    asm volatile("s_barrier" ::: "memory");
  }

  // Epilogue. C/D layout: col = lane&15, row = (lane>>4)*4 + reg.
#pragma unroll
  for (int fi = 0; fi < 8; ++fi) {
    const int srow = wm * 128 + fi * 16 + lq * 4;
#pragma unroll
    for (int j = 0; j < 4; ++j) {
      const int col = wn * 64 + j * 16 + lr;
      const float bv = bias[nb0 + col];
      if (mode == 2) {
        // featsT[t][f][s]; one t per 256-row tile; 4 s contiguous -> 8B store
        const int t = m0 >> 8;
        ushort4 h;
        h.x = f2bf(acc[fi][j][0] + bv);
        h.y = f2bf(acc[fi][j][1] + bv);
        h.z = f2bf(acc[fi][j][2] + bv);
        h.w = f2bf(acc[fi][j][3] + bv);
        *(ushort4*)&featsT[((size_t)t * FF + nb0 + col) * SS + srow] = h;
      } else {
        unsigned short* outp = (mode == 0) ? theta : phi;
#pragma unroll
        for (int rr = 0; rr < 4; ++rr)
          outp[(size_t)(m0 + srow + rr) * AA + col] = f2bf(acc[fi][j][rr] + bv);
      }
    }
  }
}

// ---------------------------------------------------------------------------
// Generic batched 256x256-tile bt-GEMM on the proven R3 8-phase structure.
//   C[bz][m][n] = scale * sum_k A[bz][m][k] * B[bz][n][k],  M = 256 (one tile)
//   grid.x = batch * ntiles (XCD-chunk-swizzled when %8==0)
// ---------------------------------------------------------------------------
template <bool OUTF32>
__global__ __launch_bounds__(512, 2) void k_bt256(
    const unsigned short* __restrict__ A, const unsigned short* __restrict__ B,
    void* __restrict__ C, int ldA, int ldB, int K,
    long sA, long sB, long sC, int ntiles, float scale) {
  __shared__ unsigned short lds[65536];  // 128 KiB
  unsigned short* As = lds;
  unsigned short* Bs = lds + 32768;

  const int nwg = gridDim.x;
  const int hb = blockIdx.x;
  const int logical = (nwg & 7) ? hb : (hb & 7) * (nwg >> 3) + (hb >> 3);
  const int bz = logical / ntiles;
  const int n0 = (logical % ntiles) * 256;

  const int tid = threadIdx.x;
  const int wave = tid >> 6, lane = tid & 63;
  const int wm = wave >> 2, wn = wave & 3;
  const int lr = lane & 15, lq = lane >> 4;
  const int brow = (wn & 1) * 64;

  const unsigned short* Ap = A + (size_t)bz * sA;                      // [256][ldA]
  const unsigned short* Bp = B + (size_t)bz * sB + (size_t)n0 * ldB;   // [256][ldB]

  floatx4 acc[8][4];
#pragma unroll
  for (int i = 0; i < 8; i++)
#pragma unroll
    for (int j = 0; j < 4; j++) acc[i][j] = (floatx4)0.0f;

  short8 af[4][2], af1[4][2], bf[4][2];
  const int NKT = K / 64;

  PROLOGUE_256(Ap, ldA, Bp, ldB)
#pragma unroll 1
  KLOOP_256(Ap, ldA, Bp, ldB, NKT)

  const int ldC = ntiles * 256;
#pragma unroll
  for (int fi = 0; fi < 8; ++fi) {
    const int srow = wm * 128 + fi * 16 + lq * 4;
#pragma unroll
    for (int j = 0; j < 4; ++j) {
      const int col = n0 + wn * 64 + j * 16 + lr;
#pragma unroll
      for (int rr = 0; rr < 4; ++rr) {
        const float v = acc[fi][j][rr] * scale;
        if (OUTF32) {
          float* Cb = (float*)C + (size_t)bz * sC;
          Cb[(size_t)(srow + rr) * ldC + col] = v;
        } else {
          unsigned short* Cb = (unsigned short*)C + (size_t)bz * sC;
          Cb[(size_t)(srow + rr) * ldC + col] = f2bf(v);
        }
      }
    }
  }
}

// ---------------------------------------------------------------------------
extern "C" void kernel_launch(void* const* d_in, const int* in_sizes, int n_in,
                              void* d_out, int out_size, void* d_ws,
                              size_t ws_size, hipStream_t stream) {
  const float* batch = (const float*)d_in[0];
  const float* a_w   = (const float*)d_in[1];
  const float* a_b   = (const float*)d_in[2];
  const float* b_w   = (const float*)d_in[3];
  const float* b_b   = (const float*)d_in[4];
  const float* g_w   = (const float*)d_in[5];
  const float* g_b   = (const float*)d_in[6];
  float* out = (float*)d_out;

  // Workspace layout (bf16 elements). Base region = 238,026,752 B.
  unsigned short* ws     = (unsigned short*)d_ws;
  unsigned short* aT     = ws;                                   // 256x1024
  unsigned short* bT     = aT + (size_t)AA * FF;                 // 256x1024
  unsigned short* gT     = bT + (size_t)AA * FF;                 // 1024x1024
  unsigned short* theta  = gT + (size_t)FF * FF;                 // 65536x256
  unsigned short* phi    = theta + (size_t)TT * SS * AA;         // 65536x256
  unsigned short* featsT = phi + (size_t)TT * SS * AA;           // [t][f][s]
  unsigned short* attn   = featsT + (size_t)TT * FF * SS;        // [t][s][r]

  const size_t base_bytes  = 238026752ull;
  const size_t batch_bytes = (size_t)TT * SS * FF * 2;  // 128 MB bf16
  if (ws_size >= base_bytes + batch_bytes) {
    // Full path: one fused prep dispatch (cvt + 3 transposes), then a single
    // 1536-block proj dispatch.
    unsigned short* batchH = attn + (size_t)TT * SS * SS;
    k_prep<<<3584, 256, 0, stream>>>(batch, batchH, a_w, aT, b_w, bT, g_w, gT);
    k_proj5<<<6 * 256, 512, 0, stream>>>(batchH, aT, bT, gT, a_b, b_b, g_b,
                                         theta, phi, featsT, 0);
  } else {
    // Fallback: separate transposes; 4 chunks of 16384 rows, batchH aliases
    // attn (32 MB).
    dim3 tb(32, 8);
    k_transpose_cvt<<<dim3(32, 8),  tb, 0, stream>>>(a_w, aT, FF, AA);
    k_transpose_cvt<<<dim3(32, 8),  tb, 0, stream>>>(b_w, bT, FF, AA);
    k_transpose_cvt<<<dim3(32, 32), tb, 0, stream>>>(g_w, gT, FF, FF);
    unsigned short* batchH = attn;
    const int CHUNK_ROWS = 16384;
    for (int c = 0; c < 4; c++) {
      const float* src = batch + (size_t)c * CHUNK_ROWS * FF;
      k_cvt<<<2048, 256, 0, stream>>>(
          src, batchH, (unsigned int)((size_t)CHUNK_ROWS * FF / 8));
      k_proj5<<<6 * 64, 512, 0, stream>>>(batchH, aT, bT, gT, a_b, b_b, g_b,
                                          theta, phi, featsT, c * CHUNK_ROWS);
    }
  }

  // attn[t] = theta[t] @ phi[t]^T   (M=N=K=256, batched over t)
  k_bt256<false><<<TT, 512, 0, stream>>>(
      theta, phi, attn, AA, AA, AA,
      (long)SS * AA, (long)SS * AA, (long)SS * SS, 1, 1.0f);

  // out[t] = (attn[t] @ featsT[t]^T) / 512   (M=256, N=1024, K=256)
  k_bt256<true><<<4 * TT, 512, 0, stream>>>(
      attn, featsT, out, SS, SS, SS,
      (long)SS * SS, (long)FF * SS, (long)SS * FF, 4, 1.0f / 512.0f);
}

// Round 10
// 421.622 us; speedup vs baseline: 1.0342x; 1.0342x over previous
//
#include <hip/hip_runtime.h>
#include <stdint.h>

// Problem dims (fixed by the reference)
#define TT 256
#define SS 256
#define FF 1024
#define AA 256

typedef __attribute__((ext_vector_type(8))) short short8;
typedef __attribute__((ext_vector_type(4))) float floatx4;

// fp32 -> bf16 round-to-nearest-even
__device__ __forceinline__ unsigned short f2bf(float f) {
  unsigned int u = __float_as_uint(f);
  u += 0x7FFFu + ((u >> 16) & 1u);
  return (unsigned short)(u >> 16);
}

// async global->LDS, 16 B per lane; LDS dest = wave-uniform base + lane*16
__device__ __forceinline__ void gl_lds16(const unsigned short* g, unsigned short* l) {
  __builtin_amdgcn_global_load_lds(
      (__attribute__((address_space(1))) void*)(g),
      (__attribute__((address_space(3))) void*)(l), 16, 0, 0);
}

// ---------------------------------------------------------------------------
// Weight transpose + fp32->bf16:  WT[n][k] = bf16(W[k][n]).  W: K x N fp32.
// (fallback path)
// ---------------------------------------------------------------------------
__global__ void k_transpose_cvt(const float* __restrict__ W,
                                unsigned short* __restrict__ WT,
                                int K, int N) {
  __shared__ float tile[32][33];
  const int bk = blockIdx.x * 32, bn = blockIdx.y * 32;
  const int tx = threadIdx.x, ty = threadIdx.y;
  for (int i = ty; i < 32; i += 8)
    tile[i][tx] = W[(size_t)(bk + i) * N + bn + tx];
  __syncthreads();
  for (int i = ty; i < 32; i += 8)
    WT[(size_t)(bn + i) * K + bk + tx] = f2bf(tile[tx][i]);
}

// ---------------------------------------------------------------------------
// Bulk fp32 -> bf16 convert (fallback path).
// ---------------------------------------------------------------------------
__global__ __launch_bounds__(256) void k_cvt(const float* __restrict__ in,
                                             unsigned short* __restrict__ out,
                                             unsigned int n8) {
  unsigned int i = blockIdx.x * 256u + threadIdx.x;
  const unsigned int stride = gridDim.x * 256u;
  for (; i < n8; i += stride) {
    const size_t base = (size_t)i * 8;
    const floatx4 v0 = *(const floatx4*)(in + base);
    const floatx4 v1 = *(const floatx4*)(in + base + 4);
    ushort4 h0, h1;
    h0.x = f2bf(v0.x); h0.y = f2bf(v0.y); h0.z = f2bf(v0.z); h0.w = f2bf(v0.w);
    h1.x = f2bf(v1.x); h1.y = f2bf(v1.y); h1.z = f2bf(v1.z); h1.w = f2bf(v1.w);
    *(ushort4*)(out + base) = h0;
    *(ushort4*)(out + base + 4) = h1;
  }
}

// ---------------------------------------------------------------------------
// Fused prep: one dispatch does the full-batch fp32->bf16 convert AND the
// three weight transposes.
//   blocks [0, 2048):     grid-stride cvt of batch (65536x1024)
//   blocks [2048, 2304):  aT transpose   blocks [2304, 2560): bT transpose
//   blocks [2560, 3584):  gT transpose
// ---------------------------------------------------------------------------
__global__ __launch_bounds__(256) void k_prep(
    const float* __restrict__ batch, unsigned short* __restrict__ batchH,
    const float* __restrict__ a_w, unsigned short* __restrict__ aT,
    const float* __restrict__ b_w, unsigned short* __restrict__ bT,
    const float* __restrict__ g_w, unsigned short* __restrict__ gT) {
  const int bid = blockIdx.x;
  if (bid < 2048) {
    const unsigned int n8 = (unsigned int)((size_t)TT * SS * FF / 8);
    unsigned int i = bid * 256u + threadIdx.x;
    for (; i < n8; i += 2048u * 256u) {
      const size_t base = (size_t)i * 8;
      const floatx4 v0 = *(const floatx4*)(batch + base);
      const floatx4 v1 = *(const floatx4*)(batch + base + 4);
      ushort4 h0, h1;
      h0.x = f2bf(v0.x); h0.y = f2bf(v0.y); h0.z = f2bf(v0.z); h0.w = f2bf(v0.w);
      h1.x = f2bf(v1.x); h1.y = f2bf(v1.y); h1.z = f2bf(v1.z); h1.w = f2bf(v1.w);
      *(ushort4*)(batchH + base) = h0;
      *(ushort4*)(batchH + base + 4) = h1;
    }
  } else {
    const int t = bid - 2048;
    const float* W; unsigned short* WT; int N, bx, by;
    if (t < 256)      { W = a_w; WT = aT; N = AA; bx = t % 32;        by = t / 32; }
    else if (t < 512) { W = b_w; WT = bT; N = AA; bx = (t - 256) % 32; by = (t - 256) / 32; }
    else              { W = g_w; WT = gT; N = FF; bx = (t - 512) % 32; by = (t - 512) / 32; }
    const int K = FF;
    __shared__ float tile[32][33];
    const int bk = bx * 32, bn = by * 32;
    const int tx = threadIdx.x & 31, ty = threadIdx.x >> 5;
    for (int i = ty; i < 32; i += 8)
      tile[i][tx] = W[(size_t)(bk + i) * N + bn + tx];
    __syncthreads();
    for (int i = ty; i < 32; i += 8)
      WT[(size_t)(bn + i) * K + bk + tx] = f2bf(tile[tx][i]);
  }
}

// ---------------------------------------------------------------------------
// Shared pieces for the 256x256 / BK=64 / 8-wave 8-phase GEMM structure.
// LDS 128 KiB: A[2buf][2half][128][64] | B[...]; half-tiles staged via
// global_load_lds with counted vmcnt (never 0 mid-loop).
// T2 swizzle: LDS granule gl of row r holds global granule gl ^ (r&7)
// (pre-swizzled source, rule #21); reads use col ^ ((row&7)<<3)
// -> conflict-free (measured 0).
// ---------------------------------------------------------------------------
__device__ __forceinline__ void stage_half(const unsigned short* G, int ld,
                                           unsigned short* L, int tid) {
  // G points at (row0, k0) of a 128x64 half-tile, leading dim = ld elems.
  const int wave = tid >> 6, lane = tid & 63;
#pragma unroll
  for (int c = 0; c < 2; ++c) {
    const int chunk = c * 8 + wave;            // 16 chunks of 8 rows
    const int r = chunk * 8 + (lane >> 3);     // local row 0..127
    const int k8 = (lane & 7) ^ (lane >> 3);   // swizzled source 16B-granule
    gl_lds16(G + (size_t)r * ld + k8 * 8, L + chunk * 512);
  }
}

__device__ __forceinline__ short8 ldsfrag(const unsigned short* h, int row,
                                          int col) {
  return *(const short8*)&h[row * 64 + (col ^ ((row & 7) << 3))];
}

// The R3-verified K-loop (8 barriers / K-tile, gate ledger):
//   ph0: stage A0(kt+1); vmcnt(6) [else 0]; barrier; read af0+bf; q00; barrier
//        (outstanding after issuing A0(kt+1) = B0,B1(kt+1)+A0(kt+1) = 6, so
//         vmcnt(6) completes ALL of tile kt incl. both A halves - all waves)
//   ph1: stage A1(kt+1); read af1; q01; barrier
//   ph2: stage B0(kt+2); q10; barrier
//   ph3: stage B1(kt+2); q11; barrier
#define KLOOP_256(Ap, ldA, Bp, ldB, NKT)                                       \
  for (int kt = 0; kt < (NKT); ++kt) {                                         \
    const unsigned short* Ah = As + ((kt & 1) * 2 + wm) * 8192;                \
    const unsigned short* Bh = Bs + ((kt & 1) * 2 + (wn >> 1)) * 8192;         \
    const int nbuf = 1 - (kt & 1);                                             \
    if (kt + 1 < (NKT)) {                                                      \
      stage_half((Ap) + (size_t)(kt + 1) * 64, (ldA),                          \
                 As + (nbuf * 2 + 0) * 8192, tid);                             \
      asm volatile("s_waitcnt vmcnt(6)" ::: "memory");                         \
    } else {                                                                   \
      asm volatile("s_waitcnt vmcnt(0)" ::: "memory");                         \
    }                                                                          \
    asm volatile("s_barrier" ::: "memory");                                    \
    _Pragma("unroll") for (int i = 0; i < 4; ++i)                              \
        _Pragma("unroll") for (int ks = 0; ks < 2; ++ks)                       \
            af[i][ks] = ldsfrag(Ah, i * 16 + lr, ks * 32 + lq * 8);            \
    _Pragma("unroll") for (int j = 0; j < 4; ++j)                              \
        _Pragma("unroll") for (int ks = 0; ks < 2; ++ks)                       \
            bf[j][ks] = ldsfrag(Bh, brow + j * 16 + lr, ks * 32 + lq * 8);     \
    __builtin_amdgcn_s_setprio(1);                                             \
    _Pragma("unroll") for (int i = 0; i < 4; ++i)                              \
        _Pragma("unroll") for (int j = 0; j < 2; ++j)                          \
            _Pragma("unroll") for (int ks = 0; ks < 2; ++ks)                   \
                acc[i][j] = __builtin_amdgcn_mfma_f32_16x16x32_bf16(           \
                    af[i][ks], bf[j][ks], acc[i][j], 0, 0, 0);                 \
    __builtin_amdgcn_s_setprio(0);                                             \
    asm volatile("s_barrier" ::: "memory");                                    \
    if (kt + 1 < (NKT))                                                        \
      stage_half((Ap) + 128 * (ldA) + (size_t)(kt + 1) * 64, (ldA),            \
                 As + (nbuf * 2 + 1) * 8192, tid);                             \
    _Pragma("unroll") for (int i = 0; i < 4; ++i)                              \
        _Pragma("unroll") for (int ks = 0; ks < 2; ++ks)                       \
            af1[i][ks] = ldsfrag(Ah, 64 + i * 16 + lr, ks * 32 + lq * 8);      \
    __builtin_amdgcn_s_setprio(1);                                             \
    _Pragma("unroll") for (int i = 0; i < 4; ++i)                              \
        _Pragma("unroll") for (int j = 0; j < 2; ++j)                          \
            _Pragma("unroll") for (int ks = 0; ks < 2; ++ks)                   \
                acc[i][2 + j] = __builtin_amdgcn_mfma_f32_16x16x32_bf16(       \
                    af[i][ks], bf[2 + j][ks], acc[i][2 + j], 0, 0, 0);         \
    __builtin_amdgcn_s_setprio(0);                                             \
    asm volatile("s_barrier" ::: "memory");                                    \
    if (kt + 2 < (NKT))                                                        \
      stage_half((Bp) + (size_t)(kt + 2) * 64, (ldB),                          \
                 Bs + ((kt & 1) * 2 + 0) * 8192, tid);                         \
    __builtin_amdgcn_s_setprio(1);                                             \
    _Pragma("unroll") for (int i = 0; i < 4; ++i)                              \
        _Pragma("unroll") for (int j = 0; j < 2; ++j)                          \
            _Pragma("unroll") for (int ks = 0; ks < 2; ++ks)                   \
                acc[4 + i][j] = __builtin_amdgcn_mfma_f32_16x16x32_bf16(       \
                    af1[i][ks], bf[j][ks], acc[4 + i][j], 0, 0, 0);            \
    __builtin_amdgcn_s_setprio(0);                                             \
    asm volatile("s_barrier" ::: "memory");                                    \
    if (kt + 2 < (NKT))                                                        \
      stage_half((Bp) + 128 * (ldB) + (size_t)(kt + 2) * 64, (ldB),            \
                 Bs + ((kt & 1) * 2 + 1) * 8192, tid);                         \
    __builtin_amdgcn_s_setprio(1);                                             \
    _Pragma("unroll") for (int i = 0; i < 4; ++i)                              \
        _Pragma("unroll") for (int j = 0; j < 2; ++j)                          \
            _Pragma("unroll") for (int ks = 0; ks < 2; ++ks)                   \
                acc[4 + i][2 + j] = __builtin_amdgcn_mfma_f32_16x16x32_bf16(   \
                    af1[i][ks], bf[2 + j][ks], acc[4 + i][2 + j], 0, 0, 0);    \
    __builtin_amdgcn_s_setprio(0);                                             \
    asm volatile("s_barrier" ::: "memory");                                    \
  }

#define PROLOGUE_256(Ap, ldA, Bp, ldB)                                         \
  stage_half((Bp), (ldB), Bs + 0 * 8192, tid);                                 \
  stage_half((Bp) + 128 * (ldB), (ldB), Bs + 1 * 8192, tid);                   \
  stage_half((Ap), (ldA), As + 0 * 8192, tid);                                 \
  stage_half((Ap) + 128 * (ldA), (ldA), As + 1 * 8192, tid);                   \
  stage_half((Bp) + 64, (ldB), Bs + 2 * 8192, tid);                            \
  stage_half((Bp) + 128 * (ldB) + 64, (ldB), Bs + 3 * 8192, tid);

// ---------------------------------------------------------------------------
// Fused projection GEMM (R3 schedule — best measured: 228 us, MfmaUtil 39.7).
//   grid.x = 6*mtiles (1-D, XCD-swizzled): nt 0 -> theta, 1 -> phi,
//   2..5 -> featsT columns (nt-2)*256.
// ---------------------------------------------------------------------------
__global__ __launch_bounds__(512, 2) void k_proj3(
    const unsigned short* __restrict__ batchH,   // chunk base [mtiles*256][FF]
    const unsigned short* __restrict__ aT,
    const unsigned short* __restrict__ bT,
    const unsigned short* __restrict__ gT,
    const float* __restrict__ a_b, const float* __restrict__ b_b,
    const float* __restrict__ g_b,
    unsigned short* __restrict__ theta,
    unsigned short* __restrict__ phi,
    unsigned short* __restrict__ featsT,
    int mbase) {
  __shared__ unsigned short lds[65536];  // 128 KiB
  unsigned short* As = lds;              // [(buf*2+half)*8192]
  unsigned short* Bs = lds + 32768;

  // T1: bijective XCD-chunked swizzle (gridDim.x % 8 == 0)
  const int nwg = gridDim.x;
  const int hb = blockIdx.x;
  const int logical = (hb & 7) * (nwg >> 3) + (hb >> 3);
  const int nt = logical % 6;
  const int mtile = logical / 6;
  const int m0l = mtile * 256;   // chunk-local
  const int m0 = mbase + m0l;    // global (multiple of 256)

  const unsigned short* Wt; const float* bias; int nb0, mode;
  if (nt == 0)      { Wt = aT; bias = a_b; nb0 = 0;              mode = 0; }
  else if (nt == 1) { Wt = bT; bias = b_b; nb0 = 0;              mode = 1; }
  else              { Wt = gT; bias = g_b; nb0 = (nt - 2) * 256; mode = 2; }

  const int tid = threadIdx.x;
  const int wave = tid >> 6, lane = tid & 63;
  const int wm = wave >> 2, wn = wave & 3;
  const int lr = lane & 15, lq = lane >> 4;
  const int brow = (wn & 1) * 64;  // wave's local row base within its B half

  const unsigned short* Ap = batchH + (size_t)m0l * FF;  // [256][1024]
  const unsigned short* Bp = Wt + (size_t)nb0 * FF;      // [256][1024]

  floatx4 acc[8][4];
#pragma unroll
  for (int i = 0; i < 8; i++)
#pragma unroll
    for (int j = 0; j < 4; j++) acc[i][j] = (floatx4)0.0f;

  short8 af[4][2], af1[4][2], bf[4][2];

  PROLOGUE_256(Ap, FF, Bp, FF)
#pragma unroll 1
  KLOOP_256(Ap, FF, Bp, FF, FF / 64)

  // Epilogue. C/D layout: col = lane&15, row = (lane>>4)*4 + reg.
#pragma unroll
  for (int fi = 0; fi < 8; ++fi) {
    const int srow = wm * 128 + fi * 16 + lq * 4;
#pragma unroll
    for (int j = 0; j < 4; ++j) {
      const int col = wn * 64 + j * 16 + lr;
      const float bv = bias[nb0 + col];
      if (mode == 2) {
        // featsT[t][f][s]; one t per 256-row tile; 4 s contiguous -> 8B store
        const int t = m0 >> 8;
        ushort4 h;
        h.x = f2bf(acc[fi][j][0] + bv);
        h.y = f2bf(acc[fi][j][1] + bv);
        h.z = f2bf(acc[fi][j][2] + bv);
        h.w = f2bf(acc[fi][j][3] + bv);
        *(ushort4*)&featsT[((size_t)t * FF + nb0 + col) * SS + srow] = h;
      } else {
        unsigned short* outp = (mode == 0) ? theta : phi;
#pragma unroll
        for (int rr = 0; rr < 4; ++rr)
          outp[(size_t)(m0 + srow + rr) * AA + col] = f2bf(acc[fi][j][rr] + bv);
      }
    }
  }
}

// ---------------------------------------------------------------------------
// Generic batched 256x256-tile bt-GEMM on the same 8-phase structure.
//   C[bz][m][n] = scale * sum_k A[bz][m][k] * B[bz][n][k],  M = 256 (one tile)
//   A: [256][ldA] per batch; B rows n0..n0+255 of [..][ldB]; C ld = ntiles*256
//   grid.x = batch * ntiles (XCD-chunk-swizzled when %8==0)
// ---------------------------------------------------------------------------
template <bool OUTF32>
__global__ __launch_bounds__(512, 2) void k_bt256(
    const unsigned short* __restrict__ A, const unsigned short* __restrict__ B,
    void* __restrict__ C, int ldA, int ldB, int K,
    long sA, long sB, long sC, int ntiles, float scale) {
  __shared__ unsigned short lds[65536];  // 128 KiB
  unsigned short* As = lds;
  unsigned short* Bs = lds + 32768;

  const int nwg = gridDim.x;
  const int hb = blockIdx.x;
  const int logical = (nwg & 7) ? hb : (hb & 7) * (nwg >> 3) + (hb >> 3);
  const int bz = logical / ntiles;
  const int n0 = (logical % ntiles) * 256;

  const int tid = threadIdx.x;
  const int wave = tid >> 6, lane = tid & 63;
  const int wm = wave >> 2, wn = wave & 3;
  const int lr = lane & 15, lq = lane >> 4;
  const int brow = (wn & 1) * 64;

  const unsigned short* Ap = A + (size_t)bz * sA;                      // [256][ldA]
  const unsigned short* Bp = B + (size_t)bz * sB + (size_t)n0 * ldB;   // [256][ldB]

  floatx4 acc[8][4];
#pragma unroll
  for (int i = 0; i < 8; i++)
#pragma unroll
    for (int j = 0; j < 4; j++) acc[i][j] = (floatx4)0.0f;

  short8 af[4][2], af1[4][2], bf[4][2];
  const int NKT = K / 64;

  PROLOGUE_256(Ap, ldA, Bp, ldB)
#pragma unroll 1
  KLOOP_256(Ap, ldA, Bp, ldB, NKT)

  const int ldC = ntiles * 256;
#pragma unroll
  for (int fi = 0; fi < 8; ++fi) {
    const int srow = wm * 128 + fi * 16 + lq * 4;
#pragma unroll
    for (int j = 0; j < 4; ++j) {
      const int col = n0 + wn * 64 + j * 16 + lr;
#pragma unroll
      for (int rr = 0; rr < 4; ++rr) {
        const float v = acc[fi][j][rr] * scale;
        if (OUTF32) {
          float* Cb = (float*)C + (size_t)bz * sC;
          Cb[(size_t)(srow + rr) * ldC + col] = v;
        } else {
          unsigned short* Cb = (unsigned short*)C + (size_t)bz * sC;
          Cb[(size_t)(srow + rr) * ldC + col] = f2bf(v);
        }
      }
    }
  }
}

// ---------------------------------------------------------------------------
extern "C" void kernel_launch(void* const* d_in, const int* in_sizes, int n_in,
                              void* d_out, int out_size, void* d_ws,
                              size_t ws_size, hipStream_t stream) {
  const float* batch = (const float*)d_in[0];
  const float* a_w   = (const float*)d_in[1];
  const float* a_b   = (const float*)d_in[2];
  const float* b_w   = (const float*)d_in[3];
  const float* b_b   = (const float*)d_in[4];
  const float* g_w   = (const float*)d_in[5];
  const float* g_b   = (const float*)d_in[6];
  float* out = (float*)d_out;

  // Workspace layout (bf16 elements). Base region = 238,026,752 B.
  unsigned short* ws     = (unsigned short*)d_ws;
  unsigned short* aT     = ws;                                   // 256x1024
  unsigned short* bT     = aT + (size_t)AA * FF;                 // 256x1024
  unsigned short* gT     = bT + (size_t)AA * FF;                 // 1024x1024
  unsigned short* theta  = gT + (size_t)FF * FF;                 // 65536x256
  unsigned short* phi    = theta + (size_t)TT * SS * AA;         // 65536x256
  unsigned short* featsT = phi + (size_t)TT * SS * AA;           // [t][f][s]
  unsigned short* attn   = featsT + (size_t)TT * FF * SS;        // [t][s][r]

  const size_t base_bytes  = 238026752ull;
  const size_t batch_bytes = (size_t)TT * SS * FF * 2;  // 128 MB bf16
  if (ws_size >= base_bytes + batch_bytes) {
    // Full path: one fused prep dispatch (cvt + 3 transposes), then a single
    // 1536-block proj dispatch.
    unsigned short* batchH = attn + (size_t)TT * SS * SS;
    k_prep<<<3584, 256, 0, stream>>>(batch, batchH, a_w, aT, b_w, bT, g_w, gT);
    k_proj3<<<6 * 256, 512, 0, stream>>>(batchH, aT, bT, gT, a_b, b_b, g_b,
                                         theta, phi, featsT, 0);
  } else {
    // Fallback: separate transposes; 4 chunks of 16384 rows, batchH aliases
    // attn (32 MB).
    dim3 tb(32, 8);
    k_transpose_cvt<<<dim3(32, 8),  tb, 0, stream>>>(a_w, aT, FF, AA);
    k_transpose_cvt<<<dim3(32, 8),  tb, 0, stream>>>(b_w, bT, FF, AA);
    k_transpose_cvt<<<dim3(32, 32), tb, 0, stream>>>(g_w, gT, FF, FF);
    unsigned short* batchH = attn;
    const int CHUNK_ROWS = 16384;
    for (int c = 0; c < 4; c++) {
      const float* src = batch + (size_t)c * CHUNK_ROWS * FF;
      k_cvt<<<2048, 256, 0, stream>>>(
          src, batchH, (unsigned int)((size_t)CHUNK_ROWS * FF / 8));
      k_proj3<<<6 * 64, 512, 0, stream>>>(batchH, aT, bT, gT, a_b, b_b, g_b,
                                          theta, phi, featsT, c * CHUNK_ROWS);
    }
  }

  // attn[t] = theta[t] @ phi[t]^T   (M=N=K=256, batched over t)
  k_bt256<false><<<TT, 512, 0, stream>>>(
      theta, phi, attn, AA, AA, AA,
      (long)SS * AA, (long)SS * AA, (long)SS * SS, 1, 1.0f);

  // out[t] = (attn[t] @ featsT[t]^T) / 512   (M=256, N=1024, K=256)
  k_bt256<true><<<4 * TT, 512, 0, stream>>>(
      attn, featsT, out, SS, SS, SS,
      (long)SS * SS, (long)FF * SS, (long)SS * FF, 4, 1.0f / 512.0f);
}